// Round 7
// baseline (159.300 us; speedup 1.0000x reference)
//
#include <hip/hip_runtime.h>
#include <hip/hip_bf16.h>

// FeatureEmbedding: out[b, f+1, e] = sum_d relu(x[b,f]*W1[f,d]+b1[f,d]) * W2[f,d,e] + b2[f,e]
//                   out[b, 0,   e] = cls_token[e]
// B=4096, F=64, D=256. Output f32 [4096][65][256].

#define B_  4096
#define F_  64
#define D_  256
#define ORS (65 * 256)   // out row stride (floats)

using f32x4  = __attribute__((ext_vector_type(4))) float;
using s16x8  = __attribute__((ext_vector_type(8))) short;

__device__ __forceinline__ unsigned short to_bf16_bits(float v) {
    __hip_bfloat16 h = __float2bfloat16(v);
    return *reinterpret_cast<unsigned short*>(&h);
}

// ---------------------------------------------------------------------------
// Prep (round-3, proven): W2 f32 [f][k][e] -> W2t bf16 [f][n=e][k], k contig.
// ---------------------------------------------------------------------------
__global__ __launch_bounds__(256) void femb_prep(
    const float* __restrict__ W2, unsigned short* __restrict__ W2t)
{
    const int f  = blockIdx.x & 63;
    const int kb = blockIdx.x >> 6;   // 0..3, 64 k each
    const int t  = threadIdx.x;       // owns output column n = t

    const float* col = W2 + (size_t)f * D_ * D_ + (size_t)(kb * 64) * D_ + t;
    float r[64];
    #pragma unroll
    for (int j = 0; j < 64; ++j) r[j] = col[(size_t)j * D_];

    unsigned short* ob = W2t + (size_t)f * 65536 + t * 256 + kb * 64;
    #pragma unroll
    for (int j8 = 0; j8 < 8; ++j8) {
        union { s16x8 s; unsigned short u[8]; } pk;
        #pragma unroll
        for (int e = 0; e < 8; ++e) pk.u[e] = to_bf16_bits(r[j8 * 8 + e]);
        *reinterpret_cast<s16x8*>(ob + j8 * 8) = pk.s;
    }
}

// ---------------------------------------------------------------------------
// Main: one block = (feature, 128-row tile). 4 waves x 64 cols each.
// M streamed in 4 chunks of 32 rows: per chunk, full-K MFMA from L2-resident
// W2t (no LDS staging, NO barriers in K-loop), then immediate LDS-transpose
// epilogue (single 8.3KB buffer, lgkm-only barriers) issuing contiguous
// 1KB-row stores that remain in flight under the next chunk's compute.
// LDS ~11KB; 3 blocks/CU (12 waves). f==0 blocks also write the cls row.
// ---------------------------------------------------------------------------
__global__ __launch_bounds__(256, 3) void femb_main7(
    const float* __restrict__ x,  const float* __restrict__ W1,
    const float* __restrict__ b1, const unsigned short* __restrict__ W2t,
    const float* __restrict__ b2, const float* __restrict__ cls,
    float* __restrict__ out)
{
    __shared__ float w1s[D_];
    __shared__ float b1s[D_];
    __shared__ float xs[128];
    __shared__ __align__(16) float eb[8 * 260];   // 8 rows x 256 cols, stride 260

    const int tid  = threadIdx.x;
    const int bid  = blockIdx.x;
    const int f    = bid & 63;        // same-f blocks share bid%8 -> same XCD (W2t L2 reuse)
    const int row0 = (bid >> 6) << 7;

    w1s[tid] = W1[f * D_ + tid];
    b1s[tid] = b1[f * D_ + tid];
    if (tid < 128) xs[tid] = x[(size_t)(row0 + tid) * F_ + f];

    const int lane = tid & 63;
    const int wid  = tid >> 6;   // 0..3: 64-col group
    const int llo  = lane & 15;
    const int lhi  = lane >> 4;

    __syncthreads();

    // Per-lane B base: n = wid*64 + nt*16 + llo, k-slice lhi*8.
    // 4 lhi lanes cover one 64B line -> full-line L2 requests.
    const unsigned short* bbase = W2t + (size_t)f * 65536
                                + (size_t)(wid * 64 + llo) * 256 + lhi * 8;

    f32x4 b2v  = *reinterpret_cast<const f32x4*>(&b2[f * D_ + lane * 4]);
    f32x4 clsv = *reinterpret_cast<const f32x4*>(cls + lane * 4);

#define LOADB(BUF, KSG)                                                        \
    {                                                                          \
        _Pragma("unroll")                                                      \
        for (int nt = 0; nt < 4; ++nt)                                         \
            BUF[nt] = *reinterpret_cast<const s16x8*>(bbase + nt * 4096 + (KSG) * 32); \
    }

#define COMP(BUF, KSG)                                                         \
    {                                                                          \
        const int kg = (KSG) * 32 + lhi * 8;                                   \
        float w1r[8], b1r[8];                                                  \
        _Pragma("unroll")                                                      \
        for (int e = 0; e < 8; ++e) { w1r[e] = w1s[kg + e]; b1r[e] = b1s[kg + e]; } \
        s16x8 afrag[2];                                                        \
        _Pragma("unroll")                                                      \
        for (int mt = 0; mt < 2; ++mt) {                                       \
            union { s16x8 sv; unsigned short u[8]; } pk;                       \
            _Pragma("unroll")                                                  \
            for (int e = 0; e < 8; ++e) {                                      \
                float h = fmaf(xv[mt], w1r[e], b1r[e]);                        \
                pk.u[e] = to_bf16_bits(fmaxf(h, 0.f));                         \
            }                                                                  \
            afrag[mt] = pk.sv;                                                 \
        }                                                                      \
        _Pragma("unroll")                                                      \
        for (int nt = 0; nt < 4; ++nt)                                         \
            _Pragma("unroll")                                                  \
            for (int mt = 0; mt < 2; ++mt)                                     \
                acc[mt][nt] = __builtin_amdgcn_mfma_f32_16x16x32_bf16(         \
                    BUF[nt], afrag[mt], acc[mt][nt], 0, 0, 0);                 \
    }

    // lgkmcnt-only barrier: orders LDS without draining global stores.
#define EPI_BAR()                                                              \
    do {                                                                       \
        asm volatile("s_waitcnt lgkmcnt(0)" ::: "memory");                     \
        __builtin_amdgcn_s_barrier();                                          \
        asm volatile("" ::: "memory");                                         \
    } while (0)

    #pragma unroll
    for (int rc = 0; rc < 4; ++rc) {
        // ---- K-loop for rows [rc*32, rc*32+32), full K=256, no barriers ----
        float xv[2];
        xv[0] = xs[rc * 32 + llo];
        xv[1] = xs[rc * 32 + 16 + llo];

        f32x4 acc[2][4];
        #pragma unroll
        for (int mt = 0; mt < 2; ++mt)
            #pragma unroll
            for (int nt = 0; nt < 4; ++nt)
                acc[mt][nt] = (f32x4){0.f, 0.f, 0.f, 0.f};

        s16x8 bufA[4], bufB[4];
        LOADB(bufA, 0);
        #pragma unroll
        for (int kp = 0; kp < 4; ++kp) {
            LOADB(bufB, 2 * kp + 1);
            COMP(bufA, 2 * kp);
            if (kp < 3) LOADB(bufA, 2 * kp + 2);
            COMP(bufB, 2 * kp + 1);
        }

        // ---- Streamed epilogue: 4 sub-chunks of 8 rows ----
        // acc layout: row(chunk-local) = mt*16 + llo ; col = wid*64 + nt*16 + lhi*4 + r
        #pragma unroll
        for (int cc = 0; cc < 4; ++cc) {
            if ((llo >> 3) == (cc & 1)) {
                const int mt_ = cc >> 1;
                const int lr_ = llo & 7;
                #pragma unroll
                for (int nt = 0; nt < 4; ++nt)
                    *reinterpret_cast<f32x4*>(
                        &eb[lr_ * 260 + wid * 64 + nt * 16 + lhi * 4]) = acc[mt_][nt];
            }
            EPI_BAR();
            #pragma unroll
            for (int i = 0; i < 2; ++i) {
                const int lr_ = wid * 2 + i;
                const size_t grow = (size_t)(row0 + rc * 32 + cc * 8 + lr_);
                f32x4 v = *reinterpret_cast<const f32x4*>(&eb[lr_ * 260 + lane * 4]) + b2v;
                *reinterpret_cast<f32x4*>(out + grow * ORS + (f + 1) * D_ + lane * 4) = v;
                if (f == 0)
                    *reinterpret_cast<f32x4*>(out + grow * ORS + lane * 4) = clsv;
            }
            EPI_BAR();  // eb safe to overwrite (reads landed in VGPRs)
        }
    }
#undef LOADB
#undef COMP
#undef EPI_BAR
}

// ---------------------------------------------------------------------------
// Fallback path (round-1, proven) if ws too small: cls kernel + direct main.
// ---------------------------------------------------------------------------
__global__ void femb_cls(const float* __restrict__ cls, float* __restrict__ out)
{
    int i = blockIdx.x * 256 + threadIdx.x;
    int b = i >> 6;
    int q = i & 63;
    f32x4 v = *reinterpret_cast<const f32x4*>(cls + q * 4);
    *reinterpret_cast<f32x4*>(out + (size_t)b * ORS + q * 4) = v;
}

__global__ __launch_bounds__(256, 2) void femb_main_fb(
    const float* __restrict__ x,  const float* __restrict__ W1,
    const float* __restrict__ b1, const float* __restrict__ W2,
    const float* __restrict__ b2, float* __restrict__ out)
{
    __shared__ float w1s[D_];
    __shared__ float b1s[D_];
    __shared__ float xs[128];
    __shared__ __align__(16) unsigned short bW[256][72];

    const int tid  = threadIdx.x;
    const int bid  = blockIdx.x;
    const int f    = bid & 63;
    const int row0 = (bid >> 6) << 7;

    w1s[tid] = W1[f * D_ + tid];
    b1s[tid] = b1[f * D_ + tid];
    if (tid < 128) xs[tid] = x[(size_t)(row0 + tid) * F_ + f];

    const int lane = tid & 63;
    const int wid  = tid >> 6;
    const int wm   = wid >> 1;
    const int wn   = wid & 1;
    const int llo  = lane & 15;
    const int lhi  = lane >> 4;

    __syncthreads();

    float xv[4];
    #pragma unroll
    for (int mt = 0; mt < 4; ++mt) xv[mt] = xs[wm * 64 + mt * 16 + llo];

    f32x4 acc[4][8];
    #pragma unroll
    for (int mt = 0; mt < 4; ++mt)
        #pragma unroll
        for (int nt = 0; nt < 8; ++nt)
            acc[mt][nt] = (f32x4){0.f, 0.f, 0.f, 0.f};

    const float* w2col = W2 + (size_t)f * D_ * D_ + tid;

    for (int kb = 0; kb < 4; ++kb) {
        float r[64];
        const float* p = w2col + (size_t)(kb * 64) * D_;
        #pragma unroll
        for (int j = 0; j < 64; ++j) r[j] = p[(size_t)j * D_];

        __syncthreads();
        #pragma unroll
        for (int j8 = 0; j8 < 8; ++j8) {
            union { s16x8 s; unsigned short u[8]; } pk;
            #pragma unroll
            for (int e = 0; e < 8; ++e) pk.u[e] = to_bf16_bits(r[j8 * 8 + e]);
            *reinterpret_cast<s16x8*>(&bW[tid][j8 * 8]) = pk.s;
        }
        __syncthreads();

        #pragma unroll
        for (int ks = 0; ks < 2; ++ks) {
            const int kg = kb * 64 + ks * 32 + lhi * 8;
            float w1r[8], b1r[8];
            #pragma unroll
            for (int e = 0; e < 8; ++e) { w1r[e] = w1s[kg + e]; b1r[e] = b1s[kg + e]; }

            s16x8 afrag[4];
            #pragma unroll
            for (int mt = 0; mt < 4; ++mt) {
                union { s16x8 s; unsigned short u[8]; } pk;
                #pragma unroll
                for (int e = 0; e < 8; ++e) {
                    float h = fmaf(xv[mt], w1r[e], b1r[e]);
                    pk.u[e] = to_bf16_bits(fmaxf(h, 0.f));
                }
                afrag[mt] = pk.s;
            }

            const int kl = ks * 32 + lhi * 8;
            #pragma unroll
            for (int nt = 0; nt < 8; ++nt) {
                s16x8 bfrag = *reinterpret_cast<const s16x8*>(
                    &bW[wn * 128 + nt * 16 + llo][kl]);
                #pragma unroll
                for (int mt = 0; mt < 4; ++mt)
                    acc[mt][nt] = __builtin_amdgcn_mfma_f32_16x16x32_bf16(
                        bfrag, afrag[mt], acc[mt][nt], 0, 0, 0);
            }
        }
    }

    const float* b2f = b2 + f * D_;
    float* obase = out + (size_t)(row0 + wm * 64 + llo) * ORS
                       + (f + 1) * D_ + wn * 128 + lhi * 4;
    #pragma unroll
    for (int nt = 0; nt < 8; ++nt) {
        f32x4 bv = *reinterpret_cast<const f32x4*>(&b2f[wn * 128 + nt * 16 + lhi * 4]);
        #pragma unroll
        for (int mt = 0; mt < 4; ++mt) {
            f32x4 v = acc[mt][nt] + bv;
            *reinterpret_cast<f32x4*>(obase + (size_t)mt * 16 * ORS + nt * 16) = v;
        }
    }
}

extern "C" void kernel_launch(void* const* d_in, const int* in_sizes, int n_in,
                              void* d_out, int out_size, void* d_ws, size_t ws_size,
                              hipStream_t stream)
{
    const float* x   = (const float*)d_in[0];
    const float* W1  = (const float*)d_in[1];
    const float* b1  = (const float*)d_in[2];
    const float* W2  = (const float*)d_in[3];
    const float* b2  = (const float*)d_in[4];
    const float* cls = (const float*)d_in[5];
    float* out = (float*)d_out;

    const size_t need = (size_t)F_ * D_ * D_ * sizeof(unsigned short); // 8 MiB
    if (ws_size >= need) {
        unsigned short* W2t = (unsigned short*)d_ws;
        femb_prep<<<F_ * 4, 256, 0, stream>>>(W2, W2t);
        femb_main7<<<F_ * (B_ / 128), 256, 0, stream>>>(x, W1, b1, W2t, b2, cls, out);
    } else {
        femb_cls<<<(B_ * 64) / 256, 256, 0, stream>>>(cls, out);
        femb_main_fb<<<F_ * (B_ / 128), 256, 0, stream>>>(x, W1, b1, W2, b2, out);
    }
}

// Round 8
// 107.381 us; speedup vs baseline: 1.4835x; 1.4835x over previous
//
#include <hip/hip_runtime.h>
#include <hip/hip_bf16.h>

// FeatureEmbedding: out[b, f+1, e] = sum_d relu(x[b,f]*W1[f,d]+b1[f,d]) * W2[f,d,e] + b2[f,e]
//                   out[b, 0,   e] = cls_token[e]
// B=4096, F=64, D=256. Output f32 [4096][65][256].

#define B_  4096
#define F_  64
#define D_  256
#define ORS (65 * 256)   // out row stride (floats)

using f32x4  = __attribute__((ext_vector_type(4))) float;
using s16x8  = __attribute__((ext_vector_type(8))) short;
typedef unsigned int u32;

__device__ __forceinline__ unsigned short to_bf16_bits(float v) {
    __hip_bfloat16 h = __float2bfloat16(v);
    return *reinterpret_cast<unsigned short*>(&h);
}

__device__ __forceinline__ void gload_lds16(const void* g, void* l) {
    __builtin_amdgcn_global_load_lds(
        (const __attribute__((address_space(1))) u32*)g,
        (__attribute__((address_space(3))) u32*)l, 16, 0, 0);
}

// ---------------------------------------------------------------------------
// Prep (proven r2/r5): W2 f32 [f][k][e] -> W2s bf16 [f][kb][n=e][p], p a 16B
// unit of 8 k, pre-swizzled p = j ^ (n&7). Linear 32KB copy into LDS IS the
// swizzled tile (rule 21: inverse-swizzled source + swizzled read).
// ---------------------------------------------------------------------------
__global__ __launch_bounds__(256) void femb_prep(
    const float* __restrict__ W2, unsigned short* __restrict__ W2s)
{
    const int blk = blockIdx.x;        // f*4 + kb
    const int f   = blk >> 2;
    const int kb  = blk & 3;
    const int t   = threadIdx.x;       // owns output column n = t

    const float* col = W2 + (size_t)f * D_ * D_ + (size_t)(kb * 64) * D_ + t;
    float r[64];
    #pragma unroll
    for (int j = 0; j < 64; ++j) r[j] = col[(size_t)j * D_];

    unsigned short* ob = W2s + (size_t)blk * 16384 + t * 64;
    #pragma unroll
    for (int j8 = 0; j8 < 8; ++j8) {
        union { s16x8 s; unsigned short u[8]; } pk;
        #pragma unroll
        for (int e = 0; e < 8; ++e) pk.u[e] = to_bf16_bits(r[j8 * 8 + e]);
        *reinterpret_cast<s16x8*>(ob + ((j8 ^ (t & 7)) * 8)) = pk.s;
    }
}

// ---------------------------------------------------------------------------
// Main: one block = (feature, 128-row tile). 256 threads = 4 waves (2x2).
// K-loop: r5's proven double-buffered global_load_lds staging (issue next
// tile BEFORE compute; one vmcnt-draining barrier per kb).
// Epilogue: DIRECT stores from acc (no LDS transpose) — A/B vs r5 to isolate
// whether the 1KB-row store shape matters. Per-wave nt-sweep still covers
// contiguous 64B chunks per row, which L2 merges into lines.
// f==0 blocks also write the cls row.
// ---------------------------------------------------------------------------
__global__ __launch_bounds__(256, 2) void femb_main8(
    const float* __restrict__ x,  const float* __restrict__ W1,
    const float* __restrict__ b1, const unsigned short* __restrict__ W2s,
    const float* __restrict__ b2, const float* __restrict__ cls,
    float* __restrict__ out)
{
    __shared__ float w1s[D_];
    __shared__ float b1s[D_];
    __shared__ float xs[128];
    __shared__ __align__(16) unsigned short bW[2][16384];  // 2 x 32KB staging

    const int tid  = threadIdx.x;
    const int bid  = blockIdx.x;
    const int f    = bid & 63;        // same-f blocks -> same bid%8 -> same XCD
    const int row0 = (bid >> 6) << 7;

    w1s[tid] = W1[f * D_ + tid];
    b1s[tid] = b1[f * D_ + tid];
    if (tid < 128) xs[tid] = x[(size_t)(row0 + tid) * F_ + f];

    const int lane = tid & 63;
    const int wid  = tid >> 6;
    const int wm   = wid >> 1;   // row half (64 rows)
    const int wn   = wid & 1;    // col half (128 cols)
    const int llo  = lane & 15;
    const int lhi  = lane >> 4;

    const char* gsrc = (const char*)W2s + (size_t)f * 131072; // 4 tiles * 32 KB

#define STAGE(DST, KB)                                                         \
    {                                                                          \
        const char* gt = gsrc + (KB) * 32768;                                  \
        _Pragma("unroll")                                                      \
        for (int r = 0; r < 8; ++r)                                            \
            gload_lds16(gt + tid * 16 + r * 4096,                              \
                        (char*)(DST) + tid * 16 + r * 4096);                   \
    }

    STAGE(bW[0], 0);
    __syncthreads();

    float xv[4];
    #pragma unroll
    for (int mt = 0; mt < 4; ++mt) xv[mt] = xs[wm * 64 + mt * 16 + llo];

    f32x4 acc[4][8];
    #pragma unroll
    for (int mt = 0; mt < 4; ++mt)
        #pragma unroll
        for (int nt = 0; nt < 8; ++nt)
            acc[mt][nt] = (f32x4){0.f, 0.f, 0.f, 0.f};

    #pragma unroll
    for (int kb = 0; kb < 4; ++kb) {
        const unsigned short* cur = bW[kb & 1];
        if (kb < 3) STAGE(bW[(kb & 1) ^ 1], kb + 1);  // async; drained at barrier

        #pragma unroll
        for (int ks = 0; ks < 2; ++ks) {
            const int kg = kb * 64 + ks * 32 + lhi * 8;
            float w1r[8], b1r[8];
            #pragma unroll
            for (int e = 0; e < 8; ++e) { w1r[e] = w1s[kg + e]; b1r[e] = b1s[kg + e]; }

            s16x8 afrag[4];
            #pragma unroll
            for (int mt = 0; mt < 4; ++mt) {
                union { s16x8 sv; unsigned short u[8]; } pk;
                #pragma unroll
                for (int e = 0; e < 8; ++e) {
                    float h = fmaf(xv[mt], w1r[e], b1r[e]);
                    pk.u[e] = to_bf16_bits(fmaxf(h, 0.f));
                }
                afrag[mt] = pk.sv;
            }

            // n = wn*128 + nt*16 + llo; logical slot j = ks*4+lhi; p = j ^ (llo&7)
            const int base16 = (wn * 128 + llo) * 64 + (((ks * 4 + lhi) ^ (llo & 7)) * 8);
            #pragma unroll
            for (int nt = 0; nt < 8; ++nt) {
                s16x8 bfrag = *reinterpret_cast<const s16x8*>(&cur[base16 + nt * 1024]);
                #pragma unroll
                for (int mt = 0; mt < 4; ++mt)
                    acc[mt][nt] = __builtin_amdgcn_mfma_f32_16x16x32_bf16(
                        bfrag, afrag[mt], acc[mt][nt], 0, 0, 0);
            }
        }
        __syncthreads();  // vmcnt drain: next tile ready; fences bW reuse
    }

    // ---- Direct epilogue (no LDS): acc layout (verified):
    // row = row0 + wm*64 + mt*16 + llo ; col = wn*128 + nt*16 + lhi*4 + r ----
    const float* b2f = b2 + f * D_;
    float* obase = out + (size_t)(row0 + wm * 64 + llo) * ORS
                       + (f + 1) * D_ + wn * 128 + lhi * 4;
    #pragma unroll
    for (int nt = 0; nt < 8; ++nt) {
        f32x4 bv = *reinterpret_cast<const f32x4*>(&b2f[wn * 128 + nt * 16 + lhi * 4]);
        #pragma unroll
        for (int mt = 0; mt < 4; ++mt) {
            f32x4 v = acc[mt][nt] + bv;
            *reinterpret_cast<f32x4*>(obase + (size_t)mt * 16 * ORS + nt * 16) = v;
        }
    }

    // cls rows for this block's 128 rows (only f==0 blocks; cls is L1-hot)
    if (f == 0) {
        float* cbase = out + (size_t)(row0 + wm * 64 + llo) * ORS + wn * 128 + lhi * 4;
        #pragma unroll
        for (int nt = 0; nt < 8; ++nt) {
            f32x4 cv = *reinterpret_cast<const f32x4*>(cls + wn * 128 + nt * 16 + lhi * 4);
            #pragma unroll
            for (int mt = 0; mt < 4; ++mt)
                *reinterpret_cast<f32x4*>(cbase + (size_t)mt * 16 * ORS + nt * 16) = cv;
        }
    }
#undef STAGE
}

// ---------------------------------------------------------------------------
// Fallback path (round-1, proven) if ws too small: cls kernel + direct main.
// ---------------------------------------------------------------------------
__global__ void femb_cls(const float* __restrict__ cls, float* __restrict__ out)
{
    int i = blockIdx.x * 256 + threadIdx.x;
    int b = i >> 6;
    int q = i & 63;
    f32x4 v = *reinterpret_cast<const f32x4*>(cls + q * 4);
    *reinterpret_cast<f32x4*>(out + (size_t)b * ORS + q * 4) = v;
}

__global__ __launch_bounds__(256, 2) void femb_main_fb(
    const float* __restrict__ x,  const float* __restrict__ W1,
    const float* __restrict__ b1, const float* __restrict__ W2,
    const float* __restrict__ b2, float* __restrict__ out)
{
    __shared__ float w1s[D_];
    __shared__ float b1s[D_];
    __shared__ float xs[128];
    __shared__ __align__(16) unsigned short bW[256][72];

    const int tid  = threadIdx.x;
    const int bid  = blockIdx.x;
    const int f    = bid & 63;
    const int row0 = (bid >> 6) << 7;

    w1s[tid] = W1[f * D_ + tid];
    b1s[tid] = b1[f * D_ + tid];
    if (tid < 128) xs[tid] = x[(size_t)(row0 + tid) * F_ + f];

    const int lane = tid & 63;
    const int wid  = tid >> 6;
    const int wm   = wid >> 1;
    const int wn   = wid & 1;
    const int llo  = lane & 15;
    const int lhi  = lane >> 4;

    __syncthreads();

    float xv[4];
    #pragma unroll
    for (int mt = 0; mt < 4; ++mt) xv[mt] = xs[wm * 64 + mt * 16 + llo];

    f32x4 acc[4][8];
    #pragma unroll
    for (int mt = 0; mt < 4; ++mt)
        #pragma unroll
        for (int nt = 0; nt < 8; ++nt)
            acc[mt][nt] = (f32x4){0.f, 0.f, 0.f, 0.f};

    const float* w2col = W2 + (size_t)f * D_ * D_ + tid;

    for (int kb = 0; kb < 4; ++kb) {
        float r[64];
        const float* p = w2col + (size_t)(kb * 64) * D_;
        #pragma unroll
        for (int j = 0; j < 64; ++j) r[j] = p[(size_t)j * D_];

        __syncthreads();
        #pragma unroll
        for (int j8 = 0; j8 < 8; ++j8) {
            union { s16x8 s; unsigned short u[8]; } pk;
            #pragma unroll
            for (int e = 0; e < 8; ++e) pk.u[e] = to_bf16_bits(r[j8 * 8 + e]);
            *reinterpret_cast<s16x8*>(&bW[tid][j8 * 8]) = pk.s;
        }
        __syncthreads();

        #pragma unroll
        for (int ks = 0; ks < 2; ++ks) {
            const int kg = kb * 64 + ks * 32 + lhi * 8;
            float w1r[8], b1r[8];
            #pragma unroll
            for (int e = 0; e < 8; ++e) { w1r[e] = w1s[kg + e]; b1r[e] = b1s[kg + e]; }

            s16x8 afrag[4];
            #pragma unroll
            for (int mt = 0; mt < 4; ++mt) {
                union { s16x8 s; unsigned short u[8]; } pk;
                #pragma unroll
                for (int e = 0; e < 8; ++e) {
                    float h = fmaf(xv[mt], w1r[e], b1r[e]);
                    pk.u[e] = to_bf16_bits(fmaxf(h, 0.f));
                }
                afrag[mt] = pk.s;
            }

            const int kl = ks * 32 + lhi * 8;
            #pragma unroll
            for (int nt = 0; nt < 8; ++nt) {
                s16x8 bfrag = *reinterpret_cast<const s16x8*>(
                    &bW[wn * 128 + nt * 16 + llo][kl]);
                #pragma unroll
                for (int mt = 0; mt < 4; ++mt)
                    acc[mt][nt] = __builtin_amdgcn_mfma_f32_16x16x32_bf16(
                        bfrag, afrag[mt], acc[mt][nt], 0, 0, 0);
            }
        }
    }

    const float* b2f = b2 + f * D_;
    float* obase = out + (size_t)(row0 + wm * 64 + llo) * ORS
                       + (f + 1) * D_ + wn * 128 + lhi * 4;
    #pragma unroll
    for (int nt = 0; nt < 8; ++nt) {
        f32x4 bv = *reinterpret_cast<const f32x4*>(&b2f[wn * 128 + nt * 16 + lhi * 4]);
        #pragma unroll
        for (int mt = 0; mt < 4; ++mt) {
            f32x4 v = acc[mt][nt] + bv;
            *reinterpret_cast<f32x4*>(obase + (size_t)mt * 16 * ORS + nt * 16) = v;
        }
    }
}

extern "C" void kernel_launch(void* const* d_in, const int* in_sizes, int n_in,
                              void* d_out, int out_size, void* d_ws, size_t ws_size,
                              hipStream_t stream)
{
    const float* x   = (const float*)d_in[0];
    const float* W1  = (const float*)d_in[1];
    const float* b1  = (const float*)d_in[2];
    const float* W2  = (const float*)d_in[3];
    const float* b2  = (const float*)d_in[4];
    const float* cls = (const float*)d_in[5];
    float* out = (float*)d_out;

    const size_t need = (size_t)F_ * D_ * D_ * sizeof(unsigned short); // 8 MiB
    if (ws_size >= need) {
        unsigned short* W2s = (unsigned short*)d_ws;
        femb_prep<<<F_ * 4, 256, 0, stream>>>(W2, W2s);
        femb_main8<<<F_ * (B_ / 128), 256, 0, stream>>>(x, W1, b1, W2s, b2, cls, out);
    } else {
        femb_cls<<<(B_ * 64) / 256, 256, 0, stream>>>(cls, out);
        femb_main_fb<<<F_ * (B_ / 128), 256, 0, stream>>>(x, W1, b1, W2, b2, out);
    }
}

// Round 9
// 78.033 us; speedup vs baseline: 2.0414x; 1.3761x over previous
//
#include <hip/hip_runtime.h>
#include <hip/hip_bf16.h>

// FeatureEmbedding: out[b, f+1, e] = sum_d relu(x[b,f]*W1[f,d]+b1[f,d]) * W2[f,d,e] + b2[f,e]
//                   out[b, 0,   e] = cls_token[e]
// B=4096, F=64, D=256. Output f32 [4096][65][256].

#define B_  4096
#define F_  64
#define D_  256
#define ORS (65 * 256)   // out row stride (floats)

using f32x4  = __attribute__((ext_vector_type(4))) float;
using s16x8  = __attribute__((ext_vector_type(8))) short;
typedef unsigned int u32;

__device__ __forceinline__ unsigned short to_bf16_bits(float v) {
    __hip_bfloat16 h = __float2bfloat16(v);
    return *reinterpret_cast<unsigned short*>(&h);
}

__device__ __forceinline__ void gload_lds16(const void* g, void* l) {
    __builtin_amdgcn_global_load_lds(
        (const __attribute__((address_space(1))) u32*)g,
        (__attribute__((address_space(3))) u32*)l, 16, 0, 0);
}

// ---------------------------------------------------------------------------
// Prep (proven): W2 f32 [f][k][e] -> W2s bf16 [f][kb][n=e][p], p a 16B unit of
// 8 k, pre-swizzled p = j ^ (n&7). Linear LDS copy of a 32KB block IS the
// swizzled tile (rule 21: inverse-swizzled source + swizzled read).
// ---------------------------------------------------------------------------
__global__ __launch_bounds__(256) void femb_prep(
    const float* __restrict__ W2, unsigned short* __restrict__ W2s)
{
    const int blk = blockIdx.x;        // f*4 + kb
    const int f   = blk >> 2;
    const int kb  = blk & 3;
    const int t   = threadIdx.x;       // owns output column n = t

    const float* col = W2 + (size_t)f * D_ * D_ + (size_t)(kb * 64) * D_ + t;
    float r[64];
    #pragma unroll
    for (int j = 0; j < 64; ++j) r[j] = col[(size_t)j * D_];

    unsigned short* ob = W2s + (size_t)blk * 16384 + t * 64;
    #pragma unroll
    for (int j8 = 0; j8 < 8; ++j8) {
        union { s16x8 s; unsigned short u[8]; } pk;
        #pragma unroll
        for (int e = 0; e < 8; ++e) pk.u[e] = to_bf16_bits(r[j8 * 8 + e]);
        *reinterpret_cast<s16x8*>(ob + ((j8 ^ (t & 7)) * 8)) = pk.s;
    }
}

// ---------------------------------------------------------------------------
// Main (r5 structure, proven 78µs, with ONE change: feature-grouped XCD remap).
// f = (bid&7)*8 + ((bid>>3)&7): XCD x hosts features 8x..8x+7, so each XCD's
// output writes concentrate in 8 CONSECUTIVE 1KB columns (8KB spans per row,
// better DRAM locality) and W2s per XCD = 1MB (perfect L2 residency).
// K-loop: double-buffered global_load_lds staging (issue next BEFORE compute).
// Epilogue: 8 ping-pong 16-row LDS-transpose chunks with lgkm-only barriers
// (stores never vmcnt-drained), contiguous 1KB-row stores.
// ---------------------------------------------------------------------------
__global__ __launch_bounds__(256, 2) void femb_main9(
    const float* __restrict__ x,  const float* __restrict__ W1,
    const float* __restrict__ b1, const unsigned short* __restrict__ W2s,
    const float* __restrict__ b2, const float* __restrict__ cls,
    float* __restrict__ out)
{
    __shared__ float w1s[D_];
    __shared__ float b1s[D_];
    __shared__ float xs[128];
    // K-loop: two 32KB bf16 tiles. Epilogue: two 16x260 f32 buffers (16.6KB ea).
    __shared__ __align__(16) char arena[65536];
    unsigned short* bW0 = (unsigned short*)arena;
    unsigned short* bW1 = (unsigned short*)(arena + 32768);
    float* eb0 = (float*)arena;
    float* eb1 = (float*)(arena + 16640);   // 16*260*4 bytes

    const int tid  = threadIdx.x;
    const int bid  = blockIdx.x;
    const int f    = (bid & 7) * 8 + ((bid >> 3) & 7);  // XCD-grouped features
    const int row0 = (bid >> 6) << 7;

    w1s[tid] = W1[f * D_ + tid];
    b1s[tid] = b1[f * D_ + tid];
    if (tid < 128) xs[tid] = x[(size_t)(row0 + tid) * F_ + f];

    const int lane = tid & 63;
    const int wid  = tid >> 6;
    const int wm   = wid >> 1;   // row half (64 rows)
    const int wn   = wid & 1;    // col half (128 cols)
    const int llo  = lane & 15;
    const int lhi  = lane >> 4;

    const char* gsrc = (const char*)(W2s + (size_t)f * 65536);
    f32x4 clsv = *reinterpret_cast<const f32x4*>(cls + lane * 4);

#define STAGE(DST, KB)                                                         \
    {                                                                          \
        const char* gt = gsrc + (KB) * 32768;                                  \
        _Pragma("unroll")                                                      \
        for (int r = 0; r < 8; ++r)                                            \
            gload_lds16(gt + tid * 16 + r * 4096,                              \
                        (char*)(DST) + tid * 16 + r * 4096);                   \
    }

    STAGE(bW0, 0);
    __syncthreads();

    float xv[4];
    #pragma unroll
    for (int mt = 0; mt < 4; ++mt) xv[mt] = xs[wm * 64 + mt * 16 + llo];

    f32x4 acc[4][8];
    #pragma unroll
    for (int mt = 0; mt < 4; ++mt)
        #pragma unroll
        for (int nt = 0; nt < 8; ++nt)
            acc[mt][nt] = (f32x4){0.f, 0.f, 0.f, 0.f};

    #pragma unroll
    for (int kb = 0; kb < 4; ++kb) {
        unsigned short* cur = (kb & 1) ? bW1 : bW0;
        unsigned short* nxt = (kb & 1) ? bW0 : bW1;
        if (kb < 3) STAGE(nxt, kb + 1);   // async; drained by end-of-iter barrier

        #pragma unroll
        for (int ks = 0; ks < 2; ++ks) {
            const int kg = kb * 64 + ks * 32 + lhi * 8;
            float w1r[8], b1r[8];
            #pragma unroll
            for (int e = 0; e < 8; ++e) { w1r[e] = w1s[kg + e]; b1r[e] = b1s[kg + e]; }

            s16x8 afrag[4];
            #pragma unroll
            for (int mt = 0; mt < 4; ++mt) {
                union { s16x8 sv; unsigned short u[8]; } pk;
                #pragma unroll
                for (int e = 0; e < 8; ++e) {
                    float h = fmaf(xv[mt], w1r[e], b1r[e]);
                    pk.u[e] = to_bf16_bits(fmaxf(h, 0.f));
                }
                afrag[mt] = pk.sv;
            }

            // n = wn*128 + nt*16 + llo; logical slot j = ks*4+lhi; p = j ^ (llo&7)
            const int base16 = (wn * 128 + llo) * 64 + (((ks * 4 + lhi) ^ (llo & 7)) * 8);
            #pragma unroll
            for (int nt = 0; nt < 8; ++nt) {
                s16x8 bfrag = *reinterpret_cast<const s16x8*>(&cur[base16 + nt * 1024]);
                #pragma unroll
                for (int mt = 0; mt < 4; ++mt)
                    acc[mt][nt] = __builtin_amdgcn_mfma_f32_16x16x32_bf16(
                        bfrag, afrag[mt], acc[mt][nt], 0, 0, 0);
            }
        }
        __syncthreads();  // vmcnt drain: next tile ready; also fences bW reuse
    }

    // ---- Epilogue: 8 ping-pong chunks of 16 rows; stores never drained ----
    // acc layout: row = wm*64 + mt*16 + llo ; col = wn*128 + nt*16 + lhi*4 + r.
    f32x4 b2v = *reinterpret_cast<const f32x4*>(&b2[f * D_ + lane * 4]);

#define EPI_WRITE(C, EB)                                                       \
    if (wm == ((C) >> 2)) {                                                    \
        const int mt_ = (C) & 3;                                               \
        _Pragma("unroll")                                                      \
        for (int nt = 0; nt < 8; ++nt)                                         \
            *reinterpret_cast<f32x4*>(                                         \
                &(EB)[llo * 260 + wn * 128 + nt * 16 + lhi * 4]) = acc[mt_][nt]; \
    }

#define EPI_BAR()                                                              \
    do {                                                                       \
        asm volatile("s_waitcnt lgkmcnt(0)" ::: "memory");                     \
        __builtin_amdgcn_s_barrier();                                          \
        asm volatile("" ::: "memory");                                         \
    } while (0)

#define EPI_READ(C, EB)                                                        \
    {                                                                          \
        _Pragma("unroll")                                                      \
        for (int i = 0; i < 4; ++i) {                                          \
            const int lr = wid * 4 + i;                                        \
            const size_t grow = (size_t)(row0 + (C) * 16 + lr);                \
            f32x4 v = *reinterpret_cast<const f32x4*>(                         \
                          &(EB)[lr * 260 + lane * 4]) + b2v;                   \
            *reinterpret_cast<f32x4*>(out + grow * ORS + (f + 1) * D_ + lane * 4) = v; \
            if (f == 0)                                                        \
                *reinterpret_cast<f32x4*>(out + grow * ORS + lane * 4) = clsv; \
        }                                                                      \
    }

    EPI_WRITE(0, eb0);
    EPI_BAR();
    #pragma unroll
    for (int c = 0; c < 8; ++c) {
        float* curb = (c & 1) ? eb1 : eb0;
        float* nxtb = (c & 1) ? eb0 : eb1;
        if (c < 7) EPI_WRITE(c + 1, nxtb);
        EPI_READ(c, curb);
        if (c < 7) EPI_BAR();
    }
#undef STAGE
#undef EPI_WRITE
#undef EPI_BAR
#undef EPI_READ
}

// ---------------------------------------------------------------------------
// Fallback path (round-1, proven) if ws too small: cls kernel + direct main.
// ---------------------------------------------------------------------------
__global__ void femb_cls(const float* __restrict__ cls, float* __restrict__ out)
{
    int i = blockIdx.x * 256 + threadIdx.x;
    int b = i >> 6;
    int q = i & 63;
    f32x4 v = *reinterpret_cast<const f32x4*>(cls + q * 4);
    *reinterpret_cast<f32x4*>(out + (size_t)b * ORS + q * 4) = v;
}

__global__ __launch_bounds__(256, 2) void femb_main_fb(
    const float* __restrict__ x,  const float* __restrict__ W1,
    const float* __restrict__ b1, const float* __restrict__ W2,
    const float* __restrict__ b2, float* __restrict__ out)
{
    __shared__ float w1s[D_];
    __shared__ float b1s[D_];
    __shared__ float xs[128];
    __shared__ __align__(16) unsigned short bW[256][72];

    const int tid  = threadIdx.x;
    const int bid  = blockIdx.x;
    const int f    = bid & 63;
    const int row0 = (bid >> 6) << 7;

    w1s[tid] = W1[f * D_ + tid];
    b1s[tid] = b1[f * D_ + tid];
    if (tid < 128) xs[tid] = x[(size_t)(row0 + tid) * F_ + f];

    const int lane = tid & 63;
    const int wid  = tid >> 6;
    const int wm   = wid >> 1;
    const int wn   = wid & 1;
    const int llo  = lane & 15;
    const int lhi  = lane >> 4;

    __syncthreads();

    float xv[4];
    #pragma unroll
    for (int mt = 0; mt < 4; ++mt) xv[mt] = xs[wm * 64 + mt * 16 + llo];

    f32x4 acc[4][8];
    #pragma unroll
    for (int mt = 0; mt < 4; ++mt)
        #pragma unroll
        for (int nt = 0; nt < 8; ++nt)
            acc[mt][nt] = (f32x4){0.f, 0.f, 0.f, 0.f};

    const float* w2col = W2 + (size_t)f * D_ * D_ + tid;

    for (int kb = 0; kb < 4; ++kb) {
        float r[64];
        const float* p = w2col + (size_t)(kb * 64) * D_;
        #pragma unroll
        for (int j = 0; j < 64; ++j) r[j] = p[(size_t)j * D_];

        __syncthreads();
        #pragma unroll
        for (int j8 = 0; j8 < 8; ++j8) {
            union { s16x8 s; unsigned short u[8]; } pk;
            #pragma unroll
            for (int e = 0; e < 8; ++e) pk.u[e] = to_bf16_bits(r[j8 * 8 + e]);
            *reinterpret_cast<s16x8*>(&bW[tid][j8 * 8]) = pk.s;
        }
        __syncthreads();

        #pragma unroll
        for (int ks = 0; ks < 2; ++ks) {
            const int kg = kb * 64 + ks * 32 + lhi * 8;
            float w1r[8], b1r[8];
            #pragma unroll
            for (int e = 0; e < 8; ++e) { w1r[e] = w1s[kg + e]; b1r[e] = b1s[kg + e]; }

            s16x8 afrag[4];
            #pragma unroll
            for (int mt = 0; mt < 4; ++mt) {
                union { s16x8 s; unsigned short u[8]; } pk;
                #pragma unroll
                for (int e = 0; e < 8; ++e) {
                    float h = fmaf(xv[mt], w1r[e], b1r[e]);
                    pk.u[e] = to_bf16_bits(fmaxf(h, 0.f));
                }
                afrag[mt] = pk.s;
            }

            const int kl = ks * 32 + lhi * 8;
            #pragma unroll
            for (int nt = 0; nt < 8; ++nt) {
                s16x8 bfrag = *reinterpret_cast<const s16x8*>(
                    &bW[wn * 128 + nt * 16 + llo][kl]);
                #pragma unroll
                for (int mt = 0; mt < 4; ++mt)
                    acc[mt][nt] = __builtin_amdgcn_mfma_f32_16x16x32_bf16(
                        bfrag, afrag[mt], acc[mt][nt], 0, 0, 0);
            }
        }
    }

    const float* b2f = b2 + f * D_;
    float* obase = out + (size_t)(row0 + wm * 64 + llo) * ORS
                       + (f + 1) * D_ + wn * 128 + lhi * 4;
    #pragma unroll
    for (int nt = 0; nt < 8; ++nt) {
        f32x4 bv = *reinterpret_cast<const f32x4*>(&b2f[wn * 128 + nt * 16 + lhi * 4]);
        #pragma unroll
        for (int mt = 0; mt < 4; ++mt) {
            f32x4 v = acc[mt][nt] + bv;
            *reinterpret_cast<f32x4*>(obase + (size_t)mt * 16 * ORS + nt * 16) = v;
        }
    }
}

extern "C" void kernel_launch(void* const* d_in, const int* in_sizes, int n_in,
                              void* d_out, int out_size, void* d_ws, size_t ws_size,
                              hipStream_t stream)
{
    const float* x   = (const float*)d_in[0];
    const float* W1  = (const float*)d_in[1];
    const float* b1  = (const float*)d_in[2];
    const float* W2  = (const float*)d_in[3];
    const float* b2  = (const float*)d_in[4];
    const float* cls = (const float*)d_in[5];
    float* out = (float*)d_out;

    const size_t need = (size_t)F_ * D_ * D_ * sizeof(unsigned short); // 8 MiB
    if (ws_size >= need) {
        unsigned short* W2s = (unsigned short*)d_ws;
        femb_prep<<<F_ * 4, 256, 0, stream>>>(W2, W2s);
        femb_main9<<<F_ * (B_ / 128), 256, 0, stream>>>(x, W1, b1, W2s, b2, cls, out);
    } else {
        femb_cls<<<(B_ * 64) / 256, 256, 0, stream>>>(cls, out);
        femb_main_fb<<<F_ * (B_ / 128), 256, 0, stream>>>(x, W1, b1, W2, b2, out);
    }
}

// Round 10
// 68.815 us; speedup vs baseline: 2.3149x; 1.1340x over previous
//
#include <hip/hip_runtime.h>
#include <hip/hip_bf16.h>

// FeatureEmbedding: out[b, f+1, e] = sum_d relu(x[b,f]*W1[f,d]+b1[f,d]) * W2[f,d,e] + b2[f,e]
//                   out[b, 0,   e] = cls_token[e]
// B=4096, F=64, D=256. Output f32 [4096][65][256].

#define B_  4096
#define F_  64
#define D_  256
#define ORS (65 * 256)   // out row stride (floats)

using f32x4  = __attribute__((ext_vector_type(4))) float;
using s16x8  = __attribute__((ext_vector_type(8))) short;

__device__ __forceinline__ unsigned short to_bf16_bits(float v) {
    __hip_bfloat16 h = __float2bfloat16(v);
    return *reinterpret_cast<unsigned short*>(&h);
}

// ---------------------------------------------------------------------------
// Prep: W2 f32 [f][k][e] -> W2r bf16 arranged so the main kernel's per-wave
// register loads are 1KB-contiguous: unit index
//   (((f*4 + w)*4 + nt)*8 + ks)*64 + lane ,  lane = lhi*16 + llo
// holds the 8 bf16 of W2[f][k = ks*32+lhi*8 .. +8][n = w*64+nt*16+llo].
// ---------------------------------------------------------------------------
__global__ __launch_bounds__(256) void femb_prep(
    const float* __restrict__ W2, unsigned short* __restrict__ W2r)
{
    const int blk = blockIdx.x;        // f*4 + kq (kq = 64-k quarter)
    const int f   = blk >> 2;
    const int kq  = blk & 3;
    const int t   = threadIdx.x;       // owns output column n = t

    const float* col = W2 + (size_t)f * D_ * D_ + (size_t)(kq * 64) * D_ + t;
    float r[64];
    #pragma unroll
    for (int j = 0; j < 64; ++j) r[j] = col[(size_t)j * D_];

    const int w   = t >> 6;
    const int nt  = (t >> 4) & 3;
    const int llo = t & 15;

    #pragma unroll
    for (int j8 = 0; j8 < 8; ++j8) {
        union { s16x8 s; unsigned short u[8]; } pk;
        #pragma unroll
        for (int e = 0; e < 8; ++e) pk.u[e] = to_bf16_bits(r[j8 * 8 + e]);
        const int ks   = kq * 2 + (j8 >> 2);   // global k = kq*64 + j8*8 + e
        const int lhi  = j8 & 3;
        const size_t unit = ((size_t)((f * 4 + w) * 4 + nt) * 8 + ks) * 64 + lhi * 16 + llo;
        *reinterpret_cast<s16x8*>(W2r + unit * 8) = pk.s;
    }
}

// ---------------------------------------------------------------------------
// Main: one block = (feature, 512-row group). 4 waves x 64 cols each.
// Prologue: each wave loads its whole B-stripe (64 cols x 256 k) into
// registers via 32 contiguous 1KB wave-loads (W2r layout). K-loop is then
// REGISTER-ONLY (no LDS staging, no barriers). M streamed in 16 chunks of
// 32 rows; per chunk: 64 MFMA + proven LDS-transpose epilogue (2 x 16-row
// ping-pong, lgkm-only barriers, contiguous 1KB-row stores) -> stores issue
// at 32 points per block and are never vmcnt-drained.
// LDS ~37KB, VGPR ~210 -> 2 blocks/CU. f==0 blocks also write the cls row.
// ---------------------------------------------------------------------------
__global__ __launch_bounds__(256, 2) void femb_main10(
    const float* __restrict__ x,  const float* __restrict__ W1,
    const float* __restrict__ b1, const unsigned short* __restrict__ W2r,
    const float* __restrict__ b2, const float* __restrict__ cls,
    float* __restrict__ out)
{
    __shared__ float w1s[D_];
    __shared__ float b1s[D_];
    __shared__ float xs[512];
    __shared__ __align__(16) float eb[2][16 * 260];

    const int tid  = threadIdx.x;
    const int bid  = blockIdx.x;
    const int f    = bid & 63;         // same-f blocks step by 64 -> same XCD
    const int row0 = (bid >> 6) << 9;  // 8 row-groups of 512

    w1s[tid] = W1[f * D_ + tid];
    b1s[tid] = b1[f * D_ + tid];
    xs[tid]       = x[(size_t)(row0 + tid) * F_ + f];
    xs[256 + tid] = x[(size_t)(row0 + 256 + tid) * F_ + f];

    const int lane = tid & 63;
    const int w    = tid >> 6;   // wave id = 64-col group
    const int llo  = lane & 15;
    const int lhi  = lane >> 4;

    // ---- B-stripe -> registers: 32 x 1KB contiguous wave-loads ----
    s16x8 breg[4][8];
    const unsigned short* gb = W2r + (size_t)(f * 4 + w) * 16384;
    #pragma unroll
    for (int nt = 0; nt < 4; ++nt)
        #pragma unroll
        for (int ks = 0; ks < 8; ++ks)
            breg[nt][ks] = *reinterpret_cast<const s16x8*>(
                gb + ((nt * 8 + ks) * 64 + lane) * 8);

    __syncthreads();   // xs/w1s/b1s ready

    f32x4 b2v  = *reinterpret_cast<const f32x4*>(&b2[f * D_ + lane * 4]);
    f32x4 clsv = *reinterpret_cast<const f32x4*>(cls + lane * 4);

    // lgkmcnt-only barrier: orders LDS without draining global stores.
#define EPI_BAR()                                                              \
    do {                                                                       \
        asm volatile("s_waitcnt lgkmcnt(0)" ::: "memory");                     \
        __builtin_amdgcn_s_barrier();                                          \
        asm volatile("" ::: "memory");                                         \
    } while (0)

    for (int ch = 0; ch < 16; ++ch) {
        // ---- K-loop for rows [ch*32, ch*32+32): register-only, no barriers ----
        const float xv0 = xs[ch * 32 + llo];
        const float xv1 = xs[ch * 32 + 16 + llo];

        f32x4 acc[2][4];
        #pragma unroll
        for (int mt = 0; mt < 2; ++mt)
            #pragma unroll
            for (int nt = 0; nt < 4; ++nt)
                acc[mt][nt] = (f32x4){0.f, 0.f, 0.f, 0.f};

        #pragma unroll
        for (int ks = 0; ks < 8; ++ks) {
            const int kg = ks * 32 + lhi * 8;
            f32x4 w1a = *reinterpret_cast<const f32x4*>(&w1s[kg]);
            f32x4 w1b = *reinterpret_cast<const f32x4*>(&w1s[kg + 4]);
            f32x4 b1a = *reinterpret_cast<const f32x4*>(&b1s[kg]);
            f32x4 b1b = *reinterpret_cast<const f32x4*>(&b1s[kg + 4]);

            s16x8 afrag[2];
            #pragma unroll
            for (int mt = 0; mt < 2; ++mt) {
                const float xv = mt ? xv1 : xv0;
                union { s16x8 sv; unsigned short u[8]; } pk;
                #pragma unroll
                for (int e = 0; e < 4; ++e) {
                    pk.u[e]     = to_bf16_bits(fmaxf(fmaf(xv, w1a[e], b1a[e]), 0.f));
                    pk.u[e + 4] = to_bf16_bits(fmaxf(fmaf(xv, w1b[e], b1b[e]), 0.f));
                }
                afrag[mt] = pk.sv;
            }

            #pragma unroll
            for (int nt = 0; nt < 4; ++nt)
                #pragma unroll
                for (int mt = 0; mt < 2; ++mt)
                    acc[mt][nt] = __builtin_amdgcn_mfma_f32_16x16x32_bf16(
                        breg[nt][ks], afrag[mt], acc[mt][nt], 0, 0, 0);
        }

        // ---- Epilogue: 2 sub-chunks of 16 rows; stores never drained ----
        // acc layout (verified): row = ch*32 + mt*16 + llo ;
        //                        col = w*64 + nt*16 + lhi*4 + r
        #pragma unroll
        for (int sc = 0; sc < 2; ++sc) {
            float* ebuf = eb[sc];
            #pragma unroll
            for (int nt = 0; nt < 4; ++nt)
                *reinterpret_cast<f32x4*>(
                    &ebuf[llo * 260 + w * 64 + nt * 16 + lhi * 4]) = acc[sc][nt];
            EPI_BAR();
            #pragma unroll
            for (int i = 0; i < 4; ++i) {
                const int lr = w * 4 + i;
                const size_t grow = (size_t)(row0 + ch * 32 + sc * 16 + lr);
                f32x4 v = *reinterpret_cast<const f32x4*>(&ebuf[lr * 260 + lane * 4]) + b2v;
                *reinterpret_cast<f32x4*>(out + grow * ORS + (f + 1) * D_ + lane * 4) = v;
                if (f == 0)
                    *reinterpret_cast<f32x4*>(out + grow * ORS + lane * 4) = clsv;
            }
            if (sc == 1) EPI_BAR();  // eb safe for next chunk (sc=0 bar covers eb0)
        }
    }
#undef EPI_BAR
}

// ---------------------------------------------------------------------------
// Fallback path (round-1, proven) if ws too small: cls kernel + direct main.
// ---------------------------------------------------------------------------
__global__ void femb_cls(const float* __restrict__ cls, float* __restrict__ out)
{
    int i = blockIdx.x * 256 + threadIdx.x;
    int b = i >> 6;
    int q = i & 63;
    f32x4 v = *reinterpret_cast<const f32x4*>(cls + q * 4);
    *reinterpret_cast<f32x4*>(out + (size_t)b * ORS + q * 4) = v;
}

__global__ __launch_bounds__(256, 2) void femb_main_fb(
    const float* __restrict__ x,  const float* __restrict__ W1,
    const float* __restrict__ b1, const float* __restrict__ W2,
    const float* __restrict__ b2, float* __restrict__ out)
{
    __shared__ float w1s[D_];
    __shared__ float b1s[D_];
    __shared__ float xs[128];
    __shared__ __align__(16) unsigned short bW[256][72];

    const int tid  = threadIdx.x;
    const int bid  = blockIdx.x;
    const int f    = bid & 63;
    const int row0 = (bid >> 6) << 7;

    w1s[tid] = W1[f * D_ + tid];
    b1s[tid] = b1[f * D_ + tid];
    if (tid < 128) xs[tid] = x[(size_t)(row0 + tid) * F_ + f];

    const int lane = tid & 63;
    const int wid  = tid >> 6;
    const int wm   = wid >> 1;
    const int wn   = wid & 1;
    const int llo  = lane & 15;
    const int lhi  = lane >> 4;

    __syncthreads();

    float xv[4];
    #pragma unroll
    for (int mt = 0; mt < 4; ++mt) xv[mt] = xs[wm * 64 + mt * 16 + llo];

    f32x4 acc[4][8];
    #pragma unroll
    for (int mt = 0; mt < 4; ++mt)
        #pragma unroll
        for (int nt = 0; nt < 8; ++nt)
            acc[mt][nt] = (f32x4){0.f, 0.f, 0.f, 0.f};

    const float* w2col = W2 + (size_t)f * D_ * D_ + tid;

    for (int kb = 0; kb < 4; ++kb) {
        float r[64];
        const float* p = w2col + (size_t)(kb * 64) * D_;
        #pragma unroll
        for (int j = 0; j < 64; ++j) r[j] = p[(size_t)j * D_];

        __syncthreads();
        #pragma unroll
        for (int j8 = 0; j8 < 8; ++j8) {
            union { s16x8 s; unsigned short u[8]; } pk;
            #pragma unroll
            for (int e = 0; e < 8; ++e) pk.u[e] = to_bf16_bits(r[j8 * 8 + e]);
            *reinterpret_cast<s16x8*>(&bW[tid][j8 * 8]) = pk.s;
        }
        __syncthreads();

        #pragma unroll
        for (int ks = 0; ks < 2; ++ks) {
            const int kg = kb * 64 + ks * 32 + lhi * 8;
            float w1r[8], b1r[8];
            #pragma unroll
            for (int e = 0; e < 8; ++e) { w1r[e] = w1s[kg + e]; b1r[e] = b1s[kg + e]; }

            s16x8 afrag[4];
            #pragma unroll
            for (int mt = 0; mt < 4; ++mt) {
                union { s16x8 s; unsigned short u[8]; } pk;
                #pragma unroll
                for (int e = 0; e < 8; ++e) {
                    float h = fmaf(xv[mt], w1r[e], b1r[e]);
                    pk.u[e] = to_bf16_bits(fmaxf(h, 0.f));
                }
                afrag[mt] = pk.s;
            }

            const int kl = ks * 32 + lhi * 8;
            #pragma unroll
            for (int nt = 0; nt < 8; ++nt) {
                s16x8 bfrag = *reinterpret_cast<const s16x8*>(
                    &bW[wn * 128 + nt * 16 + llo][kl]);
                #pragma unroll
                for (int mt = 0; mt < 4; ++mt)
                    acc[mt][nt] = __builtin_amdgcn_mfma_f32_16x16x32_bf16(
                        bfrag, afrag[mt], acc[mt][nt], 0, 0, 0);
            }
        }
    }

    const float* b2f = b2 + f * D_;
    float* obase = out + (size_t)(row0 + wm * 64 + llo) * ORS
                       + (f + 1) * D_ + wn * 128 + lhi * 4;
    #pragma unroll
    for (int nt = 0; nt < 8; ++nt) {
        f32x4 bv = *reinterpret_cast<const f32x4*>(&b2f[wn * 128 + nt * 16 + lhi * 4]);
        #pragma unroll
        for (int mt = 0; mt < 4; ++mt) {
            f32x4 v = acc[mt][nt] + bv;
            *reinterpret_cast<f32x4*>(obase + (size_t)mt * 16 * ORS + nt * 16) = v;
        }
    }
}

extern "C" void kernel_launch(void* const* d_in, const int* in_sizes, int n_in,
                              void* d_out, int out_size, void* d_ws, size_t ws_size,
                              hipStream_t stream)
{
    const float* x   = (const float*)d_in[0];
    const float* W1  = (const float*)d_in[1];
    const float* b1  = (const float*)d_in[2];
    const float* W2  = (const float*)d_in[3];
    const float* b2  = (const float*)d_in[4];
    const float* cls = (const float*)d_in[5];
    float* out = (float*)d_out;

    const size_t need = (size_t)F_ * D_ * D_ * sizeof(unsigned short); // 8 MiB
    if (ws_size >= need) {
        unsigned short* W2r = (unsigned short*)d_ws;
        femb_prep<<<F_ * 4, 256, 0, stream>>>(W2, W2r);
        femb_main10<<<F_ * (B_ / 512), 256, 0, stream>>>(x, W1, b1, W2r, b2, cls, out);
    } else {
        femb_cls<<<(B_ * 64) / 256, 256, 0, stream>>>(cls, out);
        femb_main_fb<<<F_ * (B_ / 128), 256, 0, stream>>>(x, W1, b1, W2, b2, out);
    }
}